// Round 1
// baseline (32381.860 us; speedup 1.0000x reference)
//
#include <hip/hip_runtime.h>
#include <math.h>

// Problem constants (ViT-Base-ish)
#define BATCH 8
#define CIN 3
#define HIMG 256
#define WIMG 256
#define PATCH 8
#define DMODEL 768
#define DEPTH 8
#define HEADS 12
#define DHEAD 64
#define MLPDIM 3072
#define NTOK 1024              // (256/8)^2
#define INNER 768              // HEADS*DHEAD
#define MROWS (BATCH * NTOK)   // 8192
#define QKVS (3 * INNER)       // 2304
#define KPATCH (CIN * PATCH * PATCH)  // 192
#define LNEPS 1e-5f
#define TQ 8

// ---------------------------------------------------------------------------
// w_conv [D, C, P, P] -> wT [K=192, D]
__global__ __launch_bounds__(256) void transpose_w_kernel(
    const float* __restrict__ wc, float* __restrict__ wt) {
  int idx = blockIdx.x * 256 + threadIdx.x;
  if (idx >= DMODEL * KPATCH) return;
  int d = idx / KPATCH, k = idx % KPATCH;
  wt[k * DMODEL + d] = wc[idx];
}

// im2col: x [B,C,H,W] -> A [MROWS, 192]; m=b*1024+ph*32+pw, k=c*64+py*8+px
__global__ __launch_bounds__(256) void im2col_kernel(
    const float* __restrict__ x, float* __restrict__ A) {
  int idx = blockIdx.x * 256 + threadIdx.x;
  if (idx >= MROWS * KPATCH) return;
  int m = idx / KPATCH, k = idx % KPATCH;
  int b = m / NTOK, n = m % NTOK;
  int ph = n / 32, pw = n % 32;
  int c = k / 64, r = k % 64;
  int py = r / 8, px = r % 8;
  A[idx] = x[((size_t)(b * CIN + c) * HIMG + ph * 8 + py) * WIMG + pw * 8 + px];
}

// ---------------------------------------------------------------------------
// Generic fp32 GEMM: C[M,N] = A[M,K] @ B[K,N] (+ epilogue)
// EPI: 0 = none; 2 = +bias +residual; 3 = +bias, exact GELU; 4 = +bias +pos_emb
// 128x128 tile, BK=16, 256 threads, 8x8 micro-tile. All dims divide tiles.
template <int EPI>
__global__ __launch_bounds__(256) void gemm_kernel(
    const float* __restrict__ Ag, const float* __restrict__ Bg,
    const float* __restrict__ bias, const float* __restrict__ res,
    float* __restrict__ Cg, int Mdim, int Ndim, int Kdim) {
  __shared__ float As[16][128];
  __shared__ float Bs[16][128];
  int tid = threadIdx.x;
  int tx = tid % 16;          // n micro index
  int ty = tid / 16;          // m micro index
  int n0 = blockIdx.x * 128;
  int m0 = blockIdx.y * 128;
  float acc[8][8] = {};

  for (int k0 = 0; k0 < Kdim; k0 += 16) {
#pragma unroll
    for (int u = 0; u < 2; ++u) {
      int s = tid + u * 256;       // 512 float4 slots
      int row = s >> 2;            // 0..127
      int kq = (s & 3) << 2;       // 0,4,8,12
      float4 v = *(const float4*)(Ag + (size_t)(m0 + row) * Kdim + k0 + kq);
      As[kq + 0][row] = v.x;
      As[kq + 1][row] = v.y;
      As[kq + 2][row] = v.z;
      As[kq + 3][row] = v.w;
    }
#pragma unroll
    for (int u = 0; u < 2; ++u) {
      int s = tid + u * 256;
      int krow = s >> 5;           // 0..15
      int nq = (s & 31) << 2;      // 0..124
      *(float4*)&Bs[krow][nq] =
          *(const float4*)(Bg + (size_t)(k0 + krow) * Ndim + n0 + nq);
    }
    __syncthreads();
#pragma unroll
    for (int k = 0; k < 16; ++k) {
      float a[8], b[8];
      *(float4*)&a[0] = *(const float4*)&As[k][ty * 8];
      *(float4*)&a[4] = *(const float4*)&As[k][ty * 8 + 4];
      *(float4*)&b[0] = *(const float4*)&Bs[k][tx * 8];
      *(float4*)&b[4] = *(const float4*)&Bs[k][tx * 8 + 4];
#pragma unroll
      for (int i = 0; i < 8; ++i)
#pragma unroll
        for (int j = 0; j < 8; ++j) acc[i][j] = fmaf(a[i], b[j], acc[i][j]);
    }
    __syncthreads();
  }

#pragma unroll
  for (int i = 0; i < 8; ++i) {
    int mrow = m0 + ty * 8 + i;
#pragma unroll
    for (int j = 0; j < 8; ++j) {
      int ncol = n0 + tx * 8 + j;
      float v = acc[i][j];
      if (EPI >= 2) v += bias[ncol];
      if (EPI == 2) v += res[(size_t)mrow * Ndim + ncol];
      if (EPI == 3) v = 0.5f * v * (1.0f + erff(v * 0.70710678118654752f));
      if (EPI == 4) v += res[(size_t)(mrow % NTOK) * Ndim + ncol];
      Cg[(size_t)mrow * Ndim + ncol] = v;
    }
  }
}

// ---------------------------------------------------------------------------
// LayerNorm over last dim (768). One block (256 thr) per row.
__global__ __launch_bounds__(256) void ln_kernel(
    const float* __restrict__ x, const float* __restrict__ w,
    const float* __restrict__ b, float* __restrict__ y) {
  int row = blockIdx.x;
  const float* xr = x + (size_t)row * DMODEL;
  float* yr = y + (size_t)row * DMODEL;
  int tid = threadIdx.x;
  float v0 = xr[tid], v1 = xr[tid + 256], v2 = xr[tid + 512];
  float s = v0 + v1 + v2;
  __shared__ float red[4];
#pragma unroll
  for (int off = 32; off >= 1; off >>= 1) s += __shfl_xor(s, off, 64);
  if ((tid & 63) == 0) red[tid >> 6] = s;
  __syncthreads();
  float mean = (red[0] + red[1] + red[2] + red[3]) * (1.0f / DMODEL);
  float d0 = v0 - mean, d1 = v1 - mean, d2 = v2 - mean;
  float sq = d0 * d0 + d1 * d1 + d2 * d2;
  __syncthreads();
#pragma unroll
  for (int off = 32; off >= 1; off >>= 1) sq += __shfl_xor(sq, off, 64);
  if ((tid & 63) == 0) red[tid >> 6] = sq;
  __syncthreads();
  float var = (red[0] + red[1] + red[2] + red[3]) * (1.0f / DMODEL);
  float rs = rsqrtf(var + LNEPS);
  yr[tid] = d0 * rs * w[tid] + b[tid];
  yr[tid + 256] = d1 * rs * w[tid + 256] + b[tid + 256];
  yr[tid + 512] = d2 * rs * w[tid + 512] + b[tid + 512];
}

// ---------------------------------------------------------------------------
// Attention: one block per (b, head, 8-query-row tile). Exact softmax.
// qkv layout per row m: [q(768) | k(768) | v(768)], head h owns cols h*64..h*64+63.
__global__ __launch_bounds__(256) void attn_kernel(
    const float* __restrict__ qkv, float* __restrict__ o) {
  __shared__ float qs[TQ][DHEAD];
  __shared__ float sc[TQ][NTOK];      // 32 KB
  __shared__ float red[TQ][32];
  __shared__ float rowl[TQ];
  __shared__ float opart[4][TQ][DHEAD];
  int tid = threadIdx.x;
  int blk = blockIdx.x;
  int nqt = NTOK / TQ;                 // 128
  int qt = blk % nqt;
  int hh = (blk / nqt) % HEADS;
  int bb = blk / (nqt * HEADS);
  int q0 = qt * TQ;
  const float scale = 0.125f;          // 64^-0.5

  const float* qb = qkv + (size_t)(bb * NTOK + q0) * QKVS + hh * DHEAD;
  for (int u = tid; u < TQ * DHEAD; u += 256) {
    int i = u >> 6, d = u & 63;
    qs[i][d] = qb[(size_t)i * QKVS + d];
  }
  __syncthreads();

  // --- scores: thread computes 2 (i) x 4 (j) tile per pass ---
  const float* kb = qkv + (size_t)(bb * NTOK) * QKVS + INNER + hh * DHEAD;
  int iq = tid >> 6;                   // wave id 0..3 -> i = 2*iq, 2*iq+1
  int jq = tid & 63;
#pragma unroll
  for (int pass = 0; pass < 4; ++pass) {
    int j0 = pass * 256 + jq * 4;
    const float* kp = kb + (size_t)j0 * QKVS;
    float a0[4] = {}, a1[4] = {};
#pragma unroll
    for (int d4 = 0; d4 < DHEAD; d4 += 4) {
      float4 qa = *(const float4*)&qs[2 * iq][d4];
      float4 qc = *(const float4*)&qs[2 * iq + 1][d4];
#pragma unroll
      for (int jj = 0; jj < 4; ++jj) {
        float4 kv = *(const float4*)(kp + (size_t)jj * QKVS + d4);
        a0[jj] += qa.x * kv.x + qa.y * kv.y + qa.z * kv.z + qa.w * kv.w;
        a1[jj] += qc.x * kv.x + qc.y * kv.y + qc.z * kv.z + qc.w * kv.w;
      }
    }
    *(float4*)&sc[2 * iq][j0] =
        make_float4(a0[0] * scale, a0[1] * scale, a0[2] * scale, a0[3] * scale);
    *(float4*)&sc[2 * iq + 1][j0] =
        make_float4(a1[0] * scale, a1[1] * scale, a1[2] * scale, a1[3] * scale);
  }
  __syncthreads();

  // --- softmax (rows of 1024) ---
  int i8 = tid >> 5;                   // 0..7
  int l32 = tid & 31;
  float mx = -1e30f;
  for (int j = l32; j < NTOK; j += 32) mx = fmaxf(mx, sc[i8][j]);
  red[i8][l32] = mx;
  __syncthreads();
  if (tid < TQ) {
    float m2 = -1e30f;
    for (int u = 0; u < 32; ++u) m2 = fmaxf(m2, red[tid][u]);
    red[tid][0] = m2;
  }
  __syncthreads();
  float mrow = red[i8][0];
  float sum = 0.f;
  for (int j = l32; j < NTOK; j += 32) {
    float p = expf(sc[i8][j] - mrow);
    sc[i8][j] = p;
    sum += p;
  }
  __syncthreads();  // everyone done reading red[i][0]
  red[i8][l32] = sum;
  __syncthreads();
  if (tid < TQ) {
    float s2 = 0.f;
    for (int u = 0; u < 32; ++u) s2 += red[tid][u];
    rowl[tid] = 1.0f / s2;
  }
  __syncthreads();

  // --- O = P @ V : group g handles 256 keys, lane d handles one dim ---
  const float* vb = qkv + (size_t)(bb * NTOK) * QKVS + 2 * INNER + hh * DHEAD;
  int g = tid >> 6;
  int d = tid & 63;
  float acc[TQ] = {};
  const float* vp = vb + (size_t)(g * 256) * QKVS + d;
  for (int j4 = 0; j4 < 256; j4 += 4) {
    float w0 = vp[(size_t)(j4 + 0) * QKVS];
    float w1 = vp[(size_t)(j4 + 1) * QKVS];
    float w2 = vp[(size_t)(j4 + 2) * QKVS];
    float w3 = vp[(size_t)(j4 + 3) * QKVS];
    int jb = g * 256 + j4;
#pragma unroll
    for (int i = 0; i < TQ; ++i) {
      float4 p4 = *(const float4*)&sc[i][jb];
      acc[i] += p4.x * w0 + p4.y * w1 + p4.z * w2 + p4.w * w3;
    }
  }
#pragma unroll
  for (int i = 0; i < TQ; ++i) opart[g][i][d] = acc[i];
  __syncthreads();
  float* ob = o + (size_t)(bb * NTOK + q0) * INNER + hh * DHEAD;
  for (int u = tid; u < TQ * DHEAD; u += 256) {
    int i = u >> 6, dd = u & 63;
    float v = opart[0][i][dd] + opart[1][i][dd] + opart[2][i][dd] +
              opart[3][i][dd];
    ob[(size_t)i * INNER + dd] = v * rowl[i];
  }
}

// ---------------------------------------------------------------------------
extern "C" void kernel_launch(void* const* d_in, const int* in_sizes, int n_in,
                              void* d_out, int out_size, void* d_ws,
                              size_t ws_size, hipStream_t stream) {
  const float* x      = (const float*)d_in[0];
  const float* w_conv = (const float*)d_in[1];
  const float* b_conv = (const float*)d_in[2];
  const float* pos    = (const float*)d_in[3];
  const float* ln1w   = (const float*)d_in[4];
  const float* ln1b   = (const float*)d_in[5];
  const float* qkvw   = (const float*)d_in[6];
  const float* outw   = (const float*)d_in[7];
  const float* outb   = (const float*)d_in[8];
  const float* ln2w   = (const float*)d_in[9];
  const float* ln2b   = (const float*)d_in[10];
  const float* w1     = (const float*)d_in[11];
  const float* b1     = (const float*)d_in[12];
  const float* w2     = (const float*)d_in[13];
  const float* b2     = (const float*)d_in[14];

  float* ws  = (float*)d_ws;
  float* h   = ws;                        // 6,291,456 floats
  float* y   = ws + 6291456;              // 6,291,456
  float* big = ws + 12582912;             // 25,165,824 (qkv / ffn1 / im2col)
  float* wT  = ws + 37748736;             // 147,456   (total ~152 MB)
  float* outp = (float*)d_out;

  dim3 blk(256);

  transpose_w_kernel<<<dim3((DMODEL * KPATCH + 255) / 256), blk, 0, stream>>>(
      w_conv, wT);
  im2col_kernel<<<dim3((MROWS * KPATCH + 255) / 256), blk, 0, stream>>>(x, big);
  // patch embed GEMM: [8192,192] @ [192,768] + b_conv + pos_emb -> h
  gemm_kernel<4><<<dim3(DMODEL / 128, MROWS / 128), blk, 0, stream>>>(
      big, wT, b_conv, pos, h, MROWS, DMODEL, KPATCH);

  for (int l = 0; l < DEPTH; ++l) {
    ln_kernel<<<dim3(MROWS), blk, 0, stream>>>(h, ln1w + l * DMODEL,
                                               ln1b + l * DMODEL, y);
    gemm_kernel<0><<<dim3(QKVS / 128, MROWS / 128), blk, 0, stream>>>(
        y, qkvw + (size_t)l * DMODEL * QKVS, nullptr, nullptr, big, MROWS,
        QKVS, DMODEL);
    attn_kernel<<<dim3(BATCH * HEADS * (NTOK / TQ)), blk, 0, stream>>>(big, y);
    gemm_kernel<2><<<dim3(DMODEL / 128, MROWS / 128), blk, 0, stream>>>(
        y, outw + (size_t)l * INNER * DMODEL, outb + l * DMODEL, h, h, MROWS,
        DMODEL, INNER);
    ln_kernel<<<dim3(MROWS), blk, 0, stream>>>(h, ln2w + l * DMODEL,
                                               ln2b + l * DMODEL, y);
    gemm_kernel<3><<<dim3(MLPDIM / 128, MROWS / 128), blk, 0, stream>>>(
        y, w1 + (size_t)l * DMODEL * MLPDIM, b1 + l * MLPDIM, nullptr, big,
        MROWS, MLPDIM, DMODEL);
    float* dst = (l == DEPTH - 1) ? outp : h;
    gemm_kernel<2><<<dim3(DMODEL / 128, MROWS / 128), blk, 0, stream>>>(
        big, w2 + (size_t)l * MLPDIM * DMODEL, b2 + l * DMODEL, h, dst, MROWS,
        DMODEL, MLPDIM);
  }
}

// Round 2
// 20734.003 us; speedup vs baseline: 1.5618x; 1.5618x over previous
//
#include <hip/hip_runtime.h>
#include <math.h>

// Problem constants (ViT-Base-ish)
#define BATCH 8
#define CIN 3
#define HIMG 256
#define WIMG 256
#define PATCH 8
#define DMODEL 768
#define DEPTH 8
#define HEADS 12
#define DHEAD 64
#define MLPDIM 3072
#define NTOK 1024              // (256/8)^2
#define INNER 768              // HEADS*DHEAD
#define MROWS (BATCH * NTOK)   // 8192
#define QKVS (3 * INNER)       // 2304
#define KPATCH (CIN * PATCH * PATCH)  // 192
#define LNEPS 1e-5f
#define QT 64                  // query rows per attn block
#define KT 64                  // key tile
#define LSTR 68                // LDS row stride: 272B = 16B-aligned, 2-way banks max

// ---------------------------------------------------------------------------
// w_conv [D, C, P, P] -> wT [K=192, D]
__global__ __launch_bounds__(256) void transpose_w_kernel(
    const float* __restrict__ wc, float* __restrict__ wt) {
  int idx = blockIdx.x * 256 + threadIdx.x;
  if (idx >= DMODEL * KPATCH) return;
  int d = idx / KPATCH, k = idx % KPATCH;
  wt[k * DMODEL + d] = wc[idx];
}

// im2col: x [B,C,H,W] -> A [MROWS, 192]; m=b*1024+ph*32+pw, k=c*64+py*8+px
__global__ __launch_bounds__(256) void im2col_kernel(
    const float* __restrict__ x, float* __restrict__ A) {
  int idx = blockIdx.x * 256 + threadIdx.x;
  if (idx >= MROWS * KPATCH) return;
  int m = idx / KPATCH, k = idx % KPATCH;
  int b = m / NTOK, n = m % NTOK;
  int ph = n / 32, pw = n % 32;
  int c = k / 64, r = k % 64;
  int py = r / 8, px = r % 8;
  A[idx] = x[((size_t)(b * CIN + c) * HIMG + ph * 8 + py) * WIMG + pw * 8 + px];
}

// ---------------------------------------------------------------------------
// Generic fp32 GEMM: C[M,N] = A[M,K] @ B[K,N] (+ epilogue)
// EPI: 0 = none; 2 = +bias +residual; 3 = +bias, exact GELU; 4 = +bias +pos_emb
// 128x128 tile, BK=16, 256 threads, 8x8 micro-tile. All dims divide tiles.
template <int EPI>
__global__ __launch_bounds__(256) void gemm_kernel(
    const float* __restrict__ Ag, const float* __restrict__ Bg,
    const float* __restrict__ bias, const float* __restrict__ res,
    float* __restrict__ Cg, int Mdim, int Ndim, int Kdim) {
  __shared__ float As[16][128];
  __shared__ float Bs[16][128];
  int tid = threadIdx.x;
  int tx = tid % 16;          // n micro index
  int ty = tid / 16;          // m micro index
  int n0 = blockIdx.x * 128;
  int m0 = blockIdx.y * 128;
  float acc[8][8] = {};

  for (int k0 = 0; k0 < Kdim; k0 += 16) {
#pragma unroll
    for (int u = 0; u < 2; ++u) {
      int s = tid + u * 256;       // 512 float4 slots
      int row = s >> 2;            // 0..127
      int kq = (s & 3) << 2;       // 0,4,8,12
      float4 v = *(const float4*)(Ag + (size_t)(m0 + row) * Kdim + k0 + kq);
      As[kq + 0][row] = v.x;
      As[kq + 1][row] = v.y;
      As[kq + 2][row] = v.z;
      As[kq + 3][row] = v.w;
    }
#pragma unroll
    for (int u = 0; u < 2; ++u) {
      int s = tid + u * 256;
      int krow = s >> 5;           // 0..15
      int nq = (s & 31) << 2;      // 0..124
      *(float4*)&Bs[krow][nq] =
          *(const float4*)(Bg + (size_t)(k0 + krow) * Ndim + n0 + nq);
    }
    __syncthreads();
#pragma unroll
    for (int k = 0; k < 16; ++k) {
      float a[8], b[8];
      *(float4*)&a[0] = *(const float4*)&As[k][ty * 8];
      *(float4*)&a[4] = *(const float4*)&As[k][ty * 8 + 4];
      *(float4*)&b[0] = *(const float4*)&Bs[k][tx * 8];
      *(float4*)&b[4] = *(const float4*)&Bs[k][tx * 8 + 4];
#pragma unroll
      for (int i = 0; i < 8; ++i)
#pragma unroll
        for (int j = 0; j < 8; ++j) acc[i][j] = fmaf(a[i], b[j], acc[i][j]);
    }
    __syncthreads();
  }

#pragma unroll
  for (int i = 0; i < 8; ++i) {
    int mrow = m0 + ty * 8 + i;
#pragma unroll
    for (int j = 0; j < 8; ++j) {
      int ncol = n0 + tx * 8 + j;
      float v = acc[i][j];
      if (EPI >= 2) v += bias[ncol];
      if (EPI == 2) v += res[(size_t)mrow * Ndim + ncol];
      if (EPI == 3) v = 0.5f * v * (1.0f + erff(v * 0.70710678118654752f));
      if (EPI == 4) v += res[(size_t)(mrow % NTOK) * Ndim + ncol];
      Cg[(size_t)mrow * Ndim + ncol] = v;
    }
  }
}

// ---------------------------------------------------------------------------
// LayerNorm over last dim (768). One block (256 thr) per row.
__global__ __launch_bounds__(256) void ln_kernel(
    const float* __restrict__ x, const float* __restrict__ w,
    const float* __restrict__ b, float* __restrict__ y) {
  int row = blockIdx.x;
  const float* xr = x + (size_t)row * DMODEL;
  float* yr = y + (size_t)row * DMODEL;
  int tid = threadIdx.x;
  float v0 = xr[tid], v1 = xr[tid + 256], v2 = xr[tid + 512];
  float s = v0 + v1 + v2;
  __shared__ float red[4];
#pragma unroll
  for (int off = 32; off >= 1; off >>= 1) s += __shfl_xor(s, off, 64);
  if ((tid & 63) == 0) red[tid >> 6] = s;
  __syncthreads();
  float mean = (red[0] + red[1] + red[2] + red[3]) * (1.0f / DMODEL);
  float d0 = v0 - mean, d1 = v1 - mean, d2 = v2 - mean;
  float sq = d0 * d0 + d1 * d1 + d2 * d2;
  __syncthreads();
#pragma unroll
  for (int off = 32; off >= 1; off >>= 1) sq += __shfl_xor(sq, off, 64);
  if ((tid & 63) == 0) red[tid >> 6] = sq;
  __syncthreads();
  float var = (red[0] + red[1] + red[2] + red[3]) * (1.0f / DMODEL);
  float rs = rsqrtf(var + LNEPS);
  yr[tid] = d0 * rs * w[tid] + b[tid];
  yr[tid + 256] = d1 * rs * w[tid + 256] + b[tid + 256];
  yr[tid + 512] = d2 * rs * w[tid + 512] + b[tid + 512];
}

// ---------------------------------------------------------------------------
// Flash-style attention: one block per (b, head, 64-query tile).
// qkv row m: [q(768) | k(768) | v(768)]; head h owns cols h*64..h*64+63.
// 256 threads: tx=tid&15 owns cols/dims {tx+16*j}, ty=tid>>4 owns rows {4*ty+i}.
// LDS: Qs (Q*scale), KPs (K tile, reused for P tile), Vt (V^T tile).
// Row stride 68 floats: 16B-aligned rows; all hot accesses <=2-way bank alias.
__global__ __launch_bounds__(256) void attn_kernel(
    const float* __restrict__ qkv, float* __restrict__ o) {
  __shared__ float Qs[QT][LSTR];
  __shared__ float KPs[KT][LSTR];
  __shared__ float Vt[DHEAD][LSTR];
  int tid = threadIdx.x;
  int tx = tid & 15;
  int ty = tid >> 4;
  int q0 = blockIdx.x * QT;
  int hh = blockIdx.y;
  int bb = blockIdx.z;

  const float* qb = qkv + (size_t)(bb * NTOK + q0) * QKVS + hh * DHEAD;
#pragma unroll
  for (int u = 0; u < 4; ++u) {
    int s = tid + u * 256;
    int row = s >> 4, c4 = (s & 15) << 2;
    float4 v = *(const float4*)(qb + (size_t)row * QKVS + c4);
    v.x *= 0.125f; v.y *= 0.125f; v.z *= 0.125f; v.w *= 0.125f;
    *(float4*)&Qs[row][c4] = v;
  }

  float m_i[4], l_i[4], oacc[4][4];
#pragma unroll
  for (int ii = 0; ii < 4; ++ii) {
    m_i[ii] = -1e30f;
    l_i[ii] = 0.f;
#pragma unroll
    for (int dd = 0; dd < 4; ++dd) oacc[ii][dd] = 0.f;
  }

  const float* kb0 = qkv + (size_t)(bb * NTOK) * QKVS + INNER + hh * DHEAD;
  const float* vb0 = kb0 + INNER;

  for (int t = 0; t < NTOK / KT; ++t) {
    __syncthreads();  // prev PV reads of KPs/Vt done before overwrite
    const float* kb = kb0 + (size_t)t * KT * QKVS;
    const float* vb = vb0 + (size_t)t * KT * QKVS;
#pragma unroll
    for (int u = 0; u < 4; ++u) {
      int s = tid + u * 256;
      int row = s >> 4, c4 = (s & 15) << 2;
      *(float4*)&KPs[row][c4] = *(const float4*)(kb + (size_t)row * QKVS + c4);
      float4 vv = *(const float4*)(vb + (size_t)row * QKVS + c4);
      Vt[c4 + 0][row] = vv.x;
      Vt[c4 + 1][row] = vv.y;
      Vt[c4 + 2][row] = vv.z;
      Vt[c4 + 3][row] = vv.w;
    }
    __syncthreads();

    // S = (Q*scale) @ K^T  -- 4x4 micro-tile per thread
    float sacc[4][4] = {};
#pragma unroll
    for (int k4 = 0; k4 < DHEAD; k4 += 4) {
      float4 qv[4], kv[4];
#pragma unroll
      for (int ii = 0; ii < 4; ++ii)
        qv[ii] = *(const float4*)&Qs[4 * ty + ii][k4];
#pragma unroll
      for (int jj = 0; jj < 4; ++jj)
        kv[jj] = *(const float4*)&KPs[tx + 16 * jj][k4];
#pragma unroll
      for (int ii = 0; ii < 4; ++ii)
#pragma unroll
        for (int jj = 0; jj < 4; ++jj)
          sacc[ii][jj] += qv[ii].x * kv[jj].x + qv[ii].y * kv[jj].y +
                          qv[ii].z * kv[jj].z + qv[ii].w * kv[jj].w;
    }

    // online softmax update (row stats across the 16 tx lanes, in-wave)
#pragma unroll
    for (int ii = 0; ii < 4; ++ii) {
      float rmax = fmaxf(fmaxf(sacc[ii][0], sacc[ii][1]),
                         fmaxf(sacc[ii][2], sacc[ii][3]));
#pragma unroll
      for (int off = 1; off < 16; off <<= 1)
        rmax = fmaxf(rmax, __shfl_xor(rmax, off, 64));
      float mnew = fmaxf(m_i[ii], rmax);
      float alpha = __expf(m_i[ii] - mnew);
      m_i[ii] = mnew;
      float rsum = 0.f;
#pragma unroll
      for (int jj = 0; jj < 4; ++jj) {
        float p = __expf(sacc[ii][jj] - mnew);
        sacc[ii][jj] = p;
        rsum += p;
      }
#pragma unroll
      for (int off = 1; off < 16; off <<= 1)
        rsum += __shfl_xor(rsum, off, 64);
      l_i[ii] = l_i[ii] * alpha + rsum;
#pragma unroll
      for (int dd = 0; dd < 4; ++dd) oacc[ii][dd] *= alpha;
    }

    __syncthreads();  // all K reads done; KPs becomes P
#pragma unroll
    for (int ii = 0; ii < 4; ++ii)
#pragma unroll
      for (int jj = 0; jj < 4; ++jj)
        KPs[4 * ty + ii][tx + 16 * jj] = sacc[ii][jj];
    __syncthreads();  // P visible to all

    // O += P @ V  (Vt holds V^T; dot4 over j)
#pragma unroll
    for (int j4 = 0; j4 < KT; j4 += 4) {
      float4 pv[4], vv[4];
#pragma unroll
      for (int ii = 0; ii < 4; ++ii)
        pv[ii] = *(const float4*)&KPs[4 * ty + ii][j4];
#pragma unroll
      for (int dd = 0; dd < 4; ++dd)
        vv[dd] = *(const float4*)&Vt[tx + 16 * dd][j4];
#pragma unroll
      for (int ii = 0; ii < 4; ++ii)
#pragma unroll
        for (int dd = 0; dd < 4; ++dd)
          oacc[ii][dd] += pv[ii].x * vv[dd].x + pv[ii].y * vv[dd].y +
                          pv[ii].z * vv[dd].z + pv[ii].w * vv[dd].w;
    }
  }

  float* ob = o + (size_t)(bb * NTOK + q0) * INNER + hh * DHEAD;
#pragma unroll
  for (int ii = 0; ii < 4; ++ii) {
    float inv = 1.0f / l_i[ii];
#pragma unroll
    for (int dd = 0; dd < 4; ++dd)
      ob[(size_t)(4 * ty + ii) * INNER + tx + 16 * dd] = oacc[ii][dd] * inv;
  }
}

// ---------------------------------------------------------------------------
extern "C" void kernel_launch(void* const* d_in, const int* in_sizes, int n_in,
                              void* d_out, int out_size, void* d_ws,
                              size_t ws_size, hipStream_t stream) {
  const float* x      = (const float*)d_in[0];
  const float* w_conv = (const float*)d_in[1];
  const float* b_conv = (const float*)d_in[2];
  const float* pos    = (const float*)d_in[3];
  const float* ln1w   = (const float*)d_in[4];
  const float* ln1b   = (const float*)d_in[5];
  const float* qkvw   = (const float*)d_in[6];
  const float* outw   = (const float*)d_in[7];
  const float* outb   = (const float*)d_in[8];
  const float* ln2w   = (const float*)d_in[9];
  const float* ln2b   = (const float*)d_in[10];
  const float* w1     = (const float*)d_in[11];
  const float* b1     = (const float*)d_in[12];
  const float* w2     = (const float*)d_in[13];
  const float* b2     = (const float*)d_in[14];

  float* ws  = (float*)d_ws;
  float* h   = ws;                        // 6,291,456 floats
  float* y   = ws + 6291456;              // 6,291,456
  float* big = ws + 12582912;             // 25,165,824 (qkv / ffn1 / im2col)
  float* wT  = ws + 37748736;             // 147,456   (total ~152 MB)
  float* outp = (float*)d_out;

  dim3 blk(256);

  transpose_w_kernel<<<dim3((DMODEL * KPATCH + 255) / 256), blk, 0, stream>>>(
      w_conv, wT);
  im2col_kernel<<<dim3((MROWS * KPATCH + 255) / 256), blk, 0, stream>>>(x, big);
  // patch embed GEMM: [8192,192] @ [192,768] + b_conv + pos_emb -> h
  gemm_kernel<4><<<dim3(DMODEL / 128, MROWS / 128), blk, 0, stream>>>(
      big, wT, b_conv, pos, h, MROWS, DMODEL, KPATCH);

  for (int l = 0; l < DEPTH; ++l) {
    ln_kernel<<<dim3(MROWS), blk, 0, stream>>>(h, ln1w + l * DMODEL,
                                               ln1b + l * DMODEL, y);
    gemm_kernel<0><<<dim3(QKVS / 128, MROWS / 128), blk, 0, stream>>>(
        y, qkvw + (size_t)l * DMODEL * QKVS, nullptr, nullptr, big, MROWS,
        QKVS, DMODEL);
    attn_kernel<<<dim3(NTOK / QT, HEADS, BATCH), blk, 0, stream>>>(big, y);
    gemm_kernel<2><<<dim3(DMODEL / 128, MROWS / 128), blk, 0, stream>>>(
        y, outw + (size_t)l * INNER * DMODEL, outb + l * DMODEL, h, h, MROWS,
        DMODEL, INNER);
    ln_kernel<<<dim3(MROWS), blk, 0, stream>>>(h, ln2w + l * DMODEL,
                                               ln2b + l * DMODEL, y);
    gemm_kernel<3><<<dim3(MLPDIM / 128, MROWS / 128), blk, 0, stream>>>(
        y, w1 + (size_t)l * DMODEL * MLPDIM, b1 + l * MLPDIM, nullptr, big,
        MROWS, MLPDIM, DMODEL);
    float* dst = (l == DEPTH - 1) ? outp : h;
    gemm_kernel<2><<<dim3(DMODEL / 128, MROWS / 128), blk, 0, stream>>>(
        big, w2 + (size_t)l * MLPDIM * DMODEL, b2 + l * DMODEL, h, dst, MROWS,
        DMODEL, MLPDIM);
  }
}

// Round 3
// 10165.807 us; speedup vs baseline: 3.1854x; 2.0396x over previous
//
#include <hip/hip_runtime.h>
#include <math.h>

// Problem constants (ViT-Base-ish)
#define BATCH 8
#define CIN 3
#define HIMG 256
#define WIMG 256
#define PATCH 8
#define DMODEL 768
#define DEPTH 8
#define HEADS 12
#define DHEAD 64
#define MLPDIM 3072
#define NTOK 1024              // (256/8)^2
#define INNER 768              // HEADS*DHEAD
#define MROWS (BATCH * NTOK)   // 8192
#define QKVS (3 * INNER)       // 2304
#define KPATCH (CIN * PATCH * PATCH)  // 192
#define LNEPS 1e-5f
#define QT 64                  // query rows per attn block
#define KT 64                  // key tile
#define LSTR 68                // LDS row stride for attn

typedef __attribute__((ext_vector_type(8))) short short8;  // 8 bf16 (4 VGPRs)
typedef __attribute__((ext_vector_type(4))) float v4f;     // MFMA accumulator

__device__ __forceinline__ float b2f(unsigned short u) {
  union { unsigned int i; float f; } x;
  x.i = (unsigned int)u << 16;
  return x.f;
}
__device__ __forceinline__ unsigned short f2b(float f) {
  union { float f; unsigned int i; } x;
  x.f = f;
  unsigned int r = x.i + 0x7FFFu + ((x.i >> 16) & 1u);  // RNE
  return (unsigned short)(r >> 16);
}

// async 16B/lane global->LDS (wave-uniform LDS base + lane*16)
#define GLL(gp, lp)                                                     \
  __builtin_amdgcn_global_load_lds(                                     \
      (const __attribute__((address_space(1))) void*)(gp),              \
      (__attribute__((address_space(3))) void*)(lp), 16, 0, 0)

// ---------------------------------------------------------------------------
// elementwise fp32 -> bf16 cast (w_conv: [768,192] already [N,K])
__global__ __launch_bounds__(256) void cast_kernel(
    const float* __restrict__ src, unsigned short* __restrict__ dst, int n) {
  int i = blockIdx.x * 256 + threadIdx.x;
  if (i < n) dst[i] = f2b(src[i]);
}

// transpose-cast: src fp32 [R,C] -> dst bf16 [C,R]. R,C multiples of 32.
__global__ __launch_bounds__(256) void transpose_cast_kernel(
    const float* __restrict__ src, unsigned short* __restrict__ dst, int R,
    int C) {
  __shared__ unsigned short t[32][33];
  int c0 = blockIdx.x * 32, r0 = blockIdx.y * 32;
  int tx = threadIdx.x & 31, ty = threadIdx.x >> 5;  // 32 x 8
#pragma unroll
  for (int u = 0; u < 4; ++u) {
    int r = r0 + ty + u * 8;
    t[ty + u * 8][tx] = f2b(src[(size_t)r * C + c0 + tx]);
  }
  __syncthreads();
#pragma unroll
  for (int u = 0; u < 4; ++u) {
    int c = c0 + ty + u * 8;
    dst[(size_t)c * R + r0 + tx] = t[tx][ty + u * 8];
  }
}

// im2col -> bf16: x [B,C,H,W] -> A [MROWS, 192]
__global__ __launch_bounds__(256) void im2col_kernel(
    const float* __restrict__ x, unsigned short* __restrict__ A) {
  int idx = blockIdx.x * 256 + threadIdx.x;
  if (idx >= MROWS * KPATCH) return;
  int m = idx / KPATCH, k = idx % KPATCH;
  int b = m / NTOK, n = m % NTOK;
  int ph = n / 32, pw = n % 32;
  int c = k / 64, r = k % 64;
  int py = r / 8, px = r % 8;
  A[idx] =
      f2b(x[((size_t)(b * CIN + c) * HIMG + ph * 8 + py) * WIMG + pw * 8 + px]);
}

// ---------------------------------------------------------------------------
// bf16 MFMA GEMM: C[M,N] = A[M,K] @ Bt[N,K]^T, fp32 accumulate.
// m97 structure: 128x128 tile, BK=32, 256 thr (4 waves, 2x2 quadrants),
// global_load_lds width 16, 16 x mfma_f32_16x16x32_bf16 per wave per K-step.
// EPI: 0 none; 2 +bias+res(fp32); 3 +bias,GELU; 4 +bias+pos_emb. OB: bf16 out.
template <int EPI, int OB>
__global__ __launch_bounds__(256) void mfma_gemm_kernel(
    const unsigned short* __restrict__ Ag, const unsigned short* __restrict__ Bt,
    const float* __restrict__ bias, const float* __restrict__ res,
    void* __restrict__ Cg, int Mdim, int Ndim, int Kdim) {
  __shared__ __align__(16) unsigned short Asm[128 * 32];
  __shared__ __align__(16) unsigned short Bsm[128 * 32];
  int tid = threadIdx.x;
  int lane = tid & 63;
  int wv = tid >> 6;
  int m0 = blockIdx.y * 128, n0 = blockIdx.x * 128;

  v4f acc[4][4] = {};

  // staging addressing: per-wave 32 rows (2 x 16-row 1KB chunks)
  int srow = lane >> 2;            // 0..15
  int schunk = (lane & 3) * 8;     // bf16 element offset in row
  const unsigned short* Aw = Ag + (size_t)(m0 + 32 * wv + srow) * Kdim + schunk;
  const unsigned short* Bw = Bt + (size_t)(n0 + 32 * wv + srow) * Kdim + schunk;
  unsigned short* As0 = Asm + (32 * wv) * 32;
  unsigned short* As1 = Asm + (32 * wv + 16) * 32;
  unsigned short* Bs0 = Bsm + (32 * wv) * 32;
  unsigned short* Bs1 = Bsm + (32 * wv + 16) * 32;

  // fragment addressing: wave quadrant
  int r0 = (wv >> 1) * 64, c0 = (wv & 1) * 64;
  int quad = lane >> 4, lr = lane & 15;
  const unsigned short* Afr = Asm + (r0 + lr) * 32 + quad * 8;
  const unsigned short* Bfr = Bsm + (c0 + lr) * 32 + quad * 8;

  for (int k0 = 0; k0 < Kdim; k0 += 32) {
    GLL(Aw + k0, As0);
    GLL(Aw + k0 + (size_t)16 * Kdim, As1);
    GLL(Bw + k0, Bs0);
    GLL(Bw + k0 + (size_t)16 * Kdim, Bs1);
    __syncthreads();
    short8 af[4], bf[4];
#pragma unroll
    for (int i = 0; i < 4; ++i) af[i] = *(const short8*)(Afr + i * 16 * 32);
#pragma unroll
    for (int j = 0; j < 4; ++j) bf[j] = *(const short8*)(Bfr + j * 16 * 32);
#pragma unroll
    for (int i = 0; i < 4; ++i)
#pragma unroll
      for (int j = 0; j < 4; ++j)
        acc[i][j] = __builtin_amdgcn_mfma_f32_16x16x32_bf16(af[i], bf[j],
                                                            acc[i][j], 0, 0, 0);
    __syncthreads();
  }

  // epilogue: C/D layout col=lane&15, row=quad*4+reg
  float* Cf = (float*)Cg;
  unsigned short* Cb = (unsigned short*)Cg;
#pragma unroll
  for (int i = 0; i < 4; ++i) {
#pragma unroll
    for (int j = 0; j < 4; ++j) {
      int ncol = n0 + c0 + 16 * j + lr;
#pragma unroll
      for (int reg = 0; reg < 4; ++reg) {
        int mrow = m0 + r0 + 16 * i + quad * 4 + reg;
        float v = acc[i][j][reg];
        if (EPI >= 2) v += bias[ncol];
        if (EPI == 2) v += res[(size_t)mrow * Ndim + ncol];
        if (EPI == 3) v = 0.5f * v * (1.0f + erff(v * 0.70710678118654752f));
        if (EPI == 4) v += res[(size_t)(mrow % NTOK) * Ndim + ncol];
        if (OB)
          Cb[(size_t)mrow * Ndim + ncol] = f2b(v);
        else
          Cf[(size_t)mrow * Ndim + ncol] = v;
      }
    }
  }
}

// ---------------------------------------------------------------------------
// LayerNorm over last dim (768), fp32 in -> bf16 out. One block per row.
__global__ __launch_bounds__(256) void ln_kernel(
    const float* __restrict__ x, const float* __restrict__ w,
    const float* __restrict__ b, unsigned short* __restrict__ y) {
  int row = blockIdx.x;
  const float* xr = x + (size_t)row * DMODEL;
  unsigned short* yr = y + (size_t)row * DMODEL;
  int tid = threadIdx.x;
  float v0 = xr[tid], v1 = xr[tid + 256], v2 = xr[tid + 512];
  float s = v0 + v1 + v2;
  __shared__ float red[4];
#pragma unroll
  for (int off = 32; off >= 1; off >>= 1) s += __shfl_xor(s, off, 64);
  if ((tid & 63) == 0) red[tid >> 6] = s;
  __syncthreads();
  float mean = (red[0] + red[1] + red[2] + red[3]) * (1.0f / DMODEL);
  float d0 = v0 - mean, d1 = v1 - mean, d2 = v2 - mean;
  float sq = d0 * d0 + d1 * d1 + d2 * d2;
  __syncthreads();
#pragma unroll
  for (int off = 32; off >= 1; off >>= 1) sq += __shfl_xor(sq, off, 64);
  if ((tid & 63) == 0) red[tid >> 6] = sq;
  __syncthreads();
  float var = (red[0] + red[1] + red[2] + red[3]) * (1.0f / DMODEL);
  float rs = rsqrtf(var + LNEPS);
  yr[tid] = f2b(d0 * rs * w[tid] + b[tid]);
  yr[tid + 256] = f2b(d1 * rs * w[tid + 256] + b[tid + 256]);
  yr[tid + 512] = f2b(d2 * rs * w[tid + 512] + b[tid + 512]);
}

// ---------------------------------------------------------------------------
// Flash-style attention, bf16 in (qkv) / bf16 out, fp32 math.
__global__ __launch_bounds__(256) void attn_kernel(
    const unsigned short* __restrict__ qkv, unsigned short* __restrict__ o) {
  __shared__ float Qs[QT][LSTR];
  __shared__ float KPs[KT][LSTR];
  __shared__ float Vt[DHEAD][LSTR];
  int tid = threadIdx.x;
  int tx = tid & 15;
  int ty = tid >> 4;
  int q0 = blockIdx.x * QT;
  int hh = blockIdx.y;
  int bb = blockIdx.z;

  const unsigned short* qb =
      qkv + (size_t)(bb * NTOK + q0) * QKVS + hh * DHEAD;
#pragma unroll
  for (int u = 0; u < 4; ++u) {
    int s = tid + u * 256;
    int row = s >> 4, c4 = (s & 15) << 2;
    ushort4 v = *(const ushort4*)(qb + (size_t)row * QKVS + c4);
    Qs[row][c4 + 0] = b2f(v.x) * 0.125f;
    Qs[row][c4 + 1] = b2f(v.y) * 0.125f;
    Qs[row][c4 + 2] = b2f(v.z) * 0.125f;
    Qs[row][c4 + 3] = b2f(v.w) * 0.125f;
  }

  float m_i[4], l_i[4], oacc[4][4];
#pragma unroll
  for (int ii = 0; ii < 4; ++ii) {
    m_i[ii] = -1e30f;
    l_i[ii] = 0.f;
#pragma unroll
    for (int dd = 0; dd < 4; ++dd) oacc[ii][dd] = 0.f;
  }

  const unsigned short* kb0 =
      qkv + (size_t)(bb * NTOK) * QKVS + INNER + hh * DHEAD;
  const unsigned short* vb0 = kb0 + INNER;

  for (int t = 0; t < NTOK / KT; ++t) {
    __syncthreads();
    const unsigned short* kb = kb0 + (size_t)t * KT * QKVS;
    const unsigned short* vb = vb0 + (size_t)t * KT * QKVS;
#pragma unroll
    for (int u = 0; u < 4; ++u) {
      int s = tid + u * 256;
      int row = s >> 4, c4 = (s & 15) << 2;
      ushort4 kv = *(const ushort4*)(kb + (size_t)row * QKVS + c4);
      KPs[row][c4 + 0] = b2f(kv.x);
      KPs[row][c4 + 1] = b2f(kv.y);
      KPs[row][c4 + 2] = b2f(kv.z);
      KPs[row][c4 + 3] = b2f(kv.w);
      ushort4 vv = *(const ushort4*)(vb + (size_t)row * QKVS + c4);
      Vt[c4 + 0][row] = b2f(vv.x);
      Vt[c4 + 1][row] = b2f(vv.y);
      Vt[c4 + 2][row] = b2f(vv.z);
      Vt[c4 + 3][row] = b2f(vv.w);
    }
    __syncthreads();

    // S = (Q*scale) @ K^T, 4x4 micro-tile
    float sacc[4][4] = {};
#pragma unroll
    for (int k4 = 0; k4 < DHEAD; k4 += 4) {
      float4 qv[4], kv[4];
#pragma unroll
      for (int ii = 0; ii < 4; ++ii)
        qv[ii] = *(const float4*)&Qs[4 * ty + ii][k4];
#pragma unroll
      for (int jj = 0; jj < 4; ++jj)
        kv[jj] = *(const float4*)&KPs[tx + 16 * jj][k4];
#pragma unroll
      for (int ii = 0; ii < 4; ++ii)
#pragma unroll
        for (int jj = 0; jj < 4; ++jj)
          sacc[ii][jj] += qv[ii].x * kv[jj].x + qv[ii].y * kv[jj].y +
                          qv[ii].z * kv[jj].z + qv[ii].w * kv[jj].w;
    }

    // online softmax
#pragma unroll
    for (int ii = 0; ii < 4; ++ii) {
      float rmax = fmaxf(fmaxf(sacc[ii][0], sacc[ii][1]),
                         fmaxf(sacc[ii][2], sacc[ii][3]));
#pragma unroll
      for (int off = 1; off < 16; off <<= 1)
        rmax = fmaxf(rmax, __shfl_xor(rmax, off, 64));
      float mnew = fmaxf(m_i[ii], rmax);
      float alpha = __expf(m_i[ii] - mnew);
      m_i[ii] = mnew;
      float rsum = 0.f;
#pragma unroll
      for (int jj = 0; jj < 4; ++jj) {
        float p = __expf(sacc[ii][jj] - mnew);
        sacc[ii][jj] = p;
        rsum += p;
      }
#pragma unroll
      for (int off = 1; off < 16; off <<= 1) rsum += __shfl_xor(rsum, off, 64);
      l_i[ii] = l_i[ii] * alpha + rsum;
#pragma unroll
      for (int dd = 0; dd < 4; ++dd) oacc[ii][dd] *= alpha;
    }

    __syncthreads();
#pragma unroll
    for (int ii = 0; ii < 4; ++ii)
#pragma unroll
      for (int jj = 0; jj < 4; ++jj)
        KPs[4 * ty + ii][tx + 16 * jj] = sacc[ii][jj];
    __syncthreads();

    // O += P @ V
#pragma unroll
    for (int j4 = 0; j4 < KT; j4 += 4) {
      float4 pv[4], vv[4];
#pragma unroll
      for (int ii = 0; ii < 4; ++ii)
        pv[ii] = *(const float4*)&KPs[4 * ty + ii][j4];
#pragma unroll
      for (int dd = 0; dd < 4; ++dd)
        vv[dd] = *(const float4*)&Vt[tx + 16 * dd][j4];
#pragma unroll
      for (int ii = 0; ii < 4; ++ii)
#pragma unroll
        for (int dd = 0; dd < 4; ++dd)
          oacc[ii][dd] += pv[ii].x * vv[dd].x + pv[ii].y * vv[dd].y +
                          pv[ii].z * vv[dd].z + pv[ii].w * vv[dd].w;
    }
  }

  unsigned short* ob = o + (size_t)(bb * NTOK + q0) * INNER + hh * DHEAD;
#pragma unroll
  for (int ii = 0; ii < 4; ++ii) {
    float inv = 1.0f / l_i[ii];
#pragma unroll
    for (int dd = 0; dd < 4; ++dd)
      ob[(size_t)(4 * ty + ii) * INNER + tx + 16 * dd] =
          f2b(oacc[ii][dd] * inv);
  }
}

// ---------------------------------------------------------------------------
extern "C" void kernel_launch(void* const* d_in, const int* in_sizes, int n_in,
                              void* d_out, int out_size, void* d_ws,
                              size_t ws_size, hipStream_t stream) {
  const float* x      = (const float*)d_in[0];
  const float* w_conv = (const float*)d_in[1];
  const float* b_conv = (const float*)d_in[2];
  const float* pos    = (const float*)d_in[3];
  const float* ln1w   = (const float*)d_in[4];
  const float* ln1b   = (const float*)d_in[5];
  const float* qkvw   = (const float*)d_in[6];
  const float* outw   = (const float*)d_in[7];
  const float* outb   = (const float*)d_in[8];
  const float* ln2w   = (const float*)d_in[9];
  const float* ln2b   = (const float*)d_in[10];
  const float* w1     = (const float*)d_in[11];
  const float* b1     = (const float*)d_in[12];
  const float* w2     = (const float*)d_in[13];
  const float* b2     = (const float*)d_in[14];

  char* ws = (char*)d_ws;
  float* h            = (float*)(ws + 0);                 // 25,165,824 B
  unsigned short* big = (unsigned short*)(ws + 25165824); // 50,331,648 B
  unsigned short* y   = (unsigned short*)(ws + 75497472); // 12,582,912 B
  unsigned short* wq  = (unsigned short*)(ws + 88080384); //  3,538,944 B
  unsigned short* wo  = (unsigned short*)(ws + 91619328); //  1,179,648 B
  unsigned short* w1t = (unsigned short*)(ws + 92798976); //  4,718,592 B
  unsigned short* w2t = (unsigned short*)(ws + 97517568); //  4,718,592 B
  unsigned short* wc  = (unsigned short*)(ws + 102236160);//    294,912 B
  float* outp = (float*)d_out;

  dim3 blk(256);

  cast_kernel<<<dim3((DMODEL * KPATCH + 255) / 256), blk, 0, stream>>>(
      w_conv, wc, DMODEL * KPATCH);
  im2col_kernel<<<dim3((MROWS * KPATCH + 255) / 256), blk, 0, stream>>>(x, big);
  // patch embed: [8192,192] @ wc[768,192]^T + b_conv + pos -> h fp32
  mfma_gemm_kernel<4, 0><<<dim3(DMODEL / 128, MROWS / 128), blk, 0, stream>>>(
      big, wc, b_conv, pos, h, MROWS, DMODEL, KPATCH);

  for (int l = 0; l < DEPTH; ++l) {
    transpose_cast_kernel<<<dim3(QKVS / 32, DMODEL / 32), blk, 0, stream>>>(
        qkvw + (size_t)l * DMODEL * QKVS, wq, DMODEL, QKVS);
    ln_kernel<<<dim3(MROWS), blk, 0, stream>>>(h, ln1w + l * DMODEL,
                                               ln1b + l * DMODEL, y);
    mfma_gemm_kernel<0, 1><<<dim3(QKVS / 128, MROWS / 128), blk, 0, stream>>>(
        y, wq, nullptr, nullptr, big, MROWS, QKVS, DMODEL);
    attn_kernel<<<dim3(NTOK / QT, HEADS, BATCH), blk, 0, stream>>>(big, y);
    transpose_cast_kernel<<<dim3(DMODEL / 32, INNER / 32), blk, 0, stream>>>(
        outw + (size_t)l * INNER * DMODEL, wo, INNER, DMODEL);
    mfma_gemm_kernel<2, 0><<<dim3(DMODEL / 128, MROWS / 128), blk, 0, stream>>>(
        y, wo, outb + l * DMODEL, h, h, MROWS, DMODEL, INNER);
    ln_kernel<<<dim3(MROWS), blk, 0, stream>>>(h, ln2w + l * DMODEL,
                                               ln2b + l * DMODEL, y);
    transpose_cast_kernel<<<dim3(MLPDIM / 32, DMODEL / 32), blk, 0, stream>>>(
        w1 + (size_t)l * DMODEL * MLPDIM, w1t, DMODEL, MLPDIM);
    mfma_gemm_kernel<3, 1><<<dim3(MLPDIM / 128, MROWS / 128), blk, 0, stream>>>(
        y, w1t, b1 + l * MLPDIM, nullptr, big, MROWS, MLPDIM, DMODEL);
    transpose_cast_kernel<<<dim3(DMODEL / 32, MLPDIM / 32), blk, 0, stream>>>(
        w2 + (size_t)l * MLPDIM * DMODEL, w2t, MLPDIM, DMODEL);
    float* dst = (l == DEPTH - 1) ? outp : h;
    mfma_gemm_kernel<2, 0><<<dim3(DMODEL / 128, MROWS / 128), blk, 0, stream>>>(
        big, w2t, b2 + l * DMODEL, h, dst, MROWS, DMODEL, MLPDIM);
  }
}

// Round 4
// 2783.954 us; speedup vs baseline: 11.6316x; 3.6516x over previous
//
#include <hip/hip_runtime.h>
#include <math.h>

// Problem constants (ViT-Base-ish)
#define BATCH 8
#define CIN 3
#define HIMG 256
#define WIMG 256
#define PATCH 8
#define DMODEL 768
#define DEPTH 8
#define HEADS 12
#define DHEAD 64
#define MLPDIM 3072
#define NTOK 1024              // (256/8)^2
#define INNER 768              // HEADS*DHEAD
#define MROWS (BATCH * NTOK)   // 8192
#define QKVS (3 * INNER)       // 2304
#define KPATCH (CIN * PATCH * PATCH)  // 192
#define LNEPS 1e-5f
#define PSTR 72                // attn LDS row stride (16B-aligned, conflict-safe)
// 0.125 (dh^-0.5) * log2(e): folded into Q so softmax uses exp2 (v_exp_f32)
#define QSCALE 0.18033688011112042f

typedef __attribute__((ext_vector_type(8))) short short8;  // 8 bf16 (4 VGPRs)
typedef __attribute__((ext_vector_type(4))) float v4f;     // MFMA accumulator

__device__ __forceinline__ float b2f(unsigned short u) {
  union { unsigned int i; float f; } x;
  x.i = (unsigned int)u << 16;
  return x.f;
}
__device__ __forceinline__ unsigned short f2b(float f) {
  union { float f; unsigned int i; } x;
  x.f = f;
  unsigned int r = x.i + 0x7FFFu + ((x.i >> 16) & 1u);  // RNE
  return (unsigned short)(r >> 16);
}
// pack 2 fp32 -> 2 bf16 in one u32, round-half-up (cheap: 4 VALU)
__device__ __forceinline__ unsigned int pkrh(float a, float b) {
  union { float f; unsigned int u; } x, y;
  x.f = a; y.f = b;
  return ((x.u + 0x8000u) >> 16) | ((y.u + 0x8000u) & 0xFFFF0000u);
}

// async 16B/lane global->LDS (wave-uniform LDS base + lane*16)
#define GLL(gp, lp)                                                     \
  __builtin_amdgcn_global_load_lds(                                     \
      (const __attribute__((address_space(1))) void*)(gp),              \
      (__attribute__((address_space(3))) void*)(lp), 16, 0, 0)

// ---------------------------------------------------------------------------
// elementwise fp32 -> bf16 cast (w_conv: [768,192] already [N,K])
__global__ __launch_bounds__(256) void cast_kernel(
    const float* __restrict__ src, unsigned short* __restrict__ dst, int n) {
  int i = blockIdx.x * 256 + threadIdx.x;
  if (i < n) dst[i] = f2b(src[i]);
}

// transpose-cast: src fp32 [R,C] -> dst bf16 [C,R]. R,C multiples of 32.
__global__ __launch_bounds__(256) void transpose_cast_kernel(
    const float* __restrict__ src, unsigned short* __restrict__ dst, int R,
    int C) {
  __shared__ unsigned short t[32][33];
  int c0 = blockIdx.x * 32, r0 = blockIdx.y * 32;
  int tx = threadIdx.x & 31, ty = threadIdx.x >> 5;  // 32 x 8
#pragma unroll
  for (int u = 0; u < 4; ++u) {
    int r = r0 + ty + u * 8;
    t[ty + u * 8][tx] = f2b(src[(size_t)r * C + c0 + tx]);
  }
  __syncthreads();
#pragma unroll
  for (int u = 0; u < 4; ++u) {
    int c = c0 + ty + u * 8;
    dst[(size_t)c * R + r0 + tx] = t[tx][ty + u * 8];
  }
}

// V transpose per layer: qkv bf16 [MROWS][QKVS] V-part -> vt [B*H][64][1024]
__global__ __launch_bounds__(256) void vtrans_kernel(
    const unsigned short* __restrict__ qkv, unsigned short* __restrict__ vt) {
  __shared__ unsigned short t[32][33];
  int k0 = blockIdx.x * 32;   // key tile
  int d0 = blockIdx.y * 32;   // dim tile within head
  int bh = blockIdx.z;        // b*HEADS+h
  int b = bh / HEADS, h = bh % HEADS;
  int tx = threadIdx.x & 31, ty = threadIdx.x >> 5;
  const unsigned short* src =
      qkv + (size_t)(b * NTOK) * QKVS + 2 * INNER + h * DHEAD;
#pragma unroll
  for (int u = 0; u < 4; ++u)
    t[ty + u * 8][tx] = src[(size_t)(k0 + ty + u * 8) * QKVS + d0 + tx];
  __syncthreads();
  unsigned short* dst = vt + ((size_t)bh * DHEAD + d0) * NTOK + k0;
#pragma unroll
  for (int u = 0; u < 4; ++u)
    dst[(size_t)(ty + u * 8) * NTOK + tx] = t[tx][ty + u * 8];
}

// im2col -> bf16: x [B,C,H,W] -> A [MROWS, 192]
__global__ __launch_bounds__(256) void im2col_kernel(
    const float* __restrict__ x, unsigned short* __restrict__ A) {
  int idx = blockIdx.x * 256 + threadIdx.x;
  if (idx >= MROWS * KPATCH) return;
  int m = idx / KPATCH, k = idx % KPATCH;
  int b = m / NTOK, n = m % NTOK;
  int ph = n / 32, pw = n % 32;
  int c = k / 64, r = k % 64;
  int py = r / 8, px = r % 8;
  A[idx] =
      f2b(x[((size_t)(b * CIN + c) * HIMG + ph * 8 + py) * WIMG + pw * 8 + px]);
}

// ---------------------------------------------------------------------------
// bf16 MFMA GEMM: C[M,N] = A[M,K] @ Bt[N,K]^T, fp32 accumulate.
// EPI: 0 none; 2 +bias+res(fp32); 3 +bias,GELU; 4 +bias+pos_emb;
//      5 qkv (scale Q columns by QSCALE, no bias). OB: bf16 out.
template <int EPI, int OB>
__global__ __launch_bounds__(256) void mfma_gemm_kernel(
    const unsigned short* __restrict__ Ag, const unsigned short* __restrict__ Bt,
    const float* __restrict__ bias, const float* __restrict__ res,
    void* __restrict__ Cg, int Mdim, int Ndim, int Kdim) {
  __shared__ __align__(16) unsigned short Asm[128 * 32];
  __shared__ __align__(16) unsigned short Bsm[128 * 32];
  int tid = threadIdx.x;
  int lane = tid & 63;
  int wv = tid >> 6;
  int m0 = blockIdx.y * 128, n0 = blockIdx.x * 128;

  v4f acc[4][4] = {};

  int srow = lane >> 2;            // 0..15
  int schunk = (lane & 3) * 8;     // bf16 element offset in row
  const unsigned short* Aw = Ag + (size_t)(m0 + 32 * wv + srow) * Kdim + schunk;
  const unsigned short* Bw = Bt + (size_t)(n0 + 32 * wv + srow) * Kdim + schunk;
  unsigned short* As0 = Asm + (32 * wv) * 32;
  unsigned short* As1 = Asm + (32 * wv + 16) * 32;
  unsigned short* Bs0 = Bsm + (32 * wv) * 32;
  unsigned short* Bs1 = Bsm + (32 * wv + 16) * 32;

  int r0 = (wv >> 1) * 64, c0 = (wv & 1) * 64;
  int quad = lane >> 4, lr = lane & 15;
  const unsigned short* Afr = Asm + (r0 + lr) * 32 + quad * 8;
  const unsigned short* Bfr = Bsm + (c0 + lr) * 32 + quad * 8;

  for (int k0 = 0; k0 < Kdim; k0 += 32) {
    GLL(Aw + k0, As0);
    GLL(Aw + k0 + (size_t)16 * Kdim, As1);
    GLL(Bw + k0, Bs0);
    GLL(Bw + k0 + (size_t)16 * Kdim, Bs1);
    __syncthreads();
    short8 af[4], bf[4];
#pragma unroll
    for (int i = 0; i < 4; ++i) af[i] = *(const short8*)(Afr + i * 16 * 32);
#pragma unroll
    for (int j = 0; j < 4; ++j) bf[j] = *(const short8*)(Bfr + j * 16 * 32);
#pragma unroll
    for (int i = 0; i < 4; ++i)
#pragma unroll
      for (int j = 0; j < 4; ++j)
        acc[i][j] = __builtin_amdgcn_mfma_f32_16x16x32_bf16(af[i], bf[j],
                                                            acc[i][j], 0, 0, 0);
    __syncthreads();
  }

  float* Cf = (float*)Cg;
  unsigned short* Cb = (unsigned short*)Cg;
#pragma unroll
  for (int i = 0; i < 4; ++i) {
#pragma unroll
    for (int j = 0; j < 4; ++j) {
      int ncol = n0 + c0 + 16 * j + lr;
#pragma unroll
      for (int reg = 0; reg < 4; ++reg) {
        int mrow = m0 + r0 + 16 * i + quad * 4 + reg;
        float v = acc[i][j][reg];
        if (EPI == 2 || EPI == 3 || EPI == 4) v += bias[ncol];
        if (EPI == 2) v += res[(size_t)mrow * Ndim + ncol];
        if (EPI == 3) v = 0.5f * v * (1.0f + erff(v * 0.70710678118654752f));
        if (EPI == 4) v += res[(size_t)(mrow % NTOK) * Ndim + ncol];
        if (EPI == 5 && ncol < INNER) v *= QSCALE;
        if (OB)
          Cb[(size_t)mrow * Ndim + ncol] = f2b(v);
        else
          Cf[(size_t)mrow * Ndim + ncol] = v;
      }
    }
  }
}

// ---------------------------------------------------------------------------
// LayerNorm over last dim (768), fp32 in -> bf16 out. One block per row.
__global__ __launch_bounds__(256) void ln_kernel(
    const float* __restrict__ x, const float* __restrict__ w,
    const float* __restrict__ b, unsigned short* __restrict__ y) {
  int row = blockIdx.x;
  const float* xr = x + (size_t)row * DMODEL;
  unsigned short* yr = y + (size_t)row * DMODEL;
  int tid = threadIdx.x;
  float v0 = xr[tid], v1 = xr[tid + 256], v2 = xr[tid + 512];
  float s = v0 + v1 + v2;
  __shared__ float red[4];
#pragma unroll
  for (int off = 32; off >= 1; off >>= 1) s += __shfl_xor(s, off, 64);
  if ((tid & 63) == 0) red[tid >> 6] = s;
  __syncthreads();
  float mean = (red[0] + red[1] + red[2] + red[3]) * (1.0f / DMODEL);
  float d0 = v0 - mean, d1 = v1 - mean, d2 = v2 - mean;
  float sq = d0 * d0 + d1 * d1 + d2 * d2;
  __syncthreads();
#pragma unroll
  for (int off = 32; off >= 1; off >>= 1) sq += __shfl_xor(sq, off, 64);
  if ((tid & 63) == 0) red[tid >> 6] = sq;
  __syncthreads();
  float var = (red[0] + red[1] + red[2] + red[3]) * (1.0f / DMODEL);
  float rs = rsqrtf(var + LNEPS);
  yr[tid] = f2b(d0 * rs * w[tid] + b[tid]);
  yr[tid + 256] = f2b(d1 * rs * w[tid + 256] + b[tid + 256]);
  yr[tid + 512] = f2b(d2 * rs * w[tid + 512] + b[tid + 512]);
}

// ---------------------------------------------------------------------------
// MFMA flash attention. Block = (128 q-rows, head, batch); 4 waves x 32 q.
// Computes S^T = K @ Q^T (C/D col = q), online softmax with in-wave shuffles,
// P packed to bf16 and written to per-wave LDS in A-fragment layout,
// O = P @ V with V^T pre-transposed globally (vtg). Q pre-scaled by QSCALE
// in the qkv GEMM epilogue -> softmax uses exp2 (native v_exp_f32).
__global__ __launch_bounds__(256) void attn_kernel(
    const unsigned short* __restrict__ qkv,
    const unsigned short* __restrict__ vtg, unsigned short* __restrict__ o) {
  __shared__ __align__(16) unsigned short Ks[64 * PSTR];
  __shared__ __align__(16) unsigned short Vs[64 * PSTR];
  __shared__ __align__(16) unsigned short Pl[4][32 * PSTR];
  int tid = threadIdx.x;
  int lane = tid & 63, wv = tid >> 6;
  int quad = lane >> 4, lr = lane & 15;
  int q0 = blockIdx.x * 128, hh = blockIdx.y, bb = blockIdx.z;

  const unsigned short* qg =
      qkv + (size_t)(bb * NTOK + q0 + wv * 32) * QKVS + hh * DHEAD;
  const unsigned short* kg =
      qkv + (size_t)(bb * NTOK) * QKVS + INNER + hh * DHEAD;
  const unsigned short* vg = vtg + (size_t)(bb * HEADS + hh) * DHEAD * NTOK;
  unsigned short* Pw = Pl[wv];

  int srow = lane >> 3, soff = (lane & 7) * 8;

  // stage this wave's 32 Q rows (already scaled) into its private Pl region
#pragma unroll
  for (int p = 0; p < 4; ++p) {
    int r = p * 8 + srow;
    *(int4*)(Pw + r * PSTR + soff) =
        *(const int4*)(qg + (size_t)r * QKVS + soff);
  }
  short8 qf[2][2];  // [q-16-group][kstep] B-fragments, kept in registers
#pragma unroll
  for (int n = 0; n < 2; ++n)
#pragma unroll
    for (int s = 0; s < 2; ++s)
      qf[n][s] =
          *(const short8*)(Pw + (n * 16 + lr) * PSTR + s * 32 + quad * 8);

  v4f oac[2][4] = {};                       // O accum [q-tile][d-tile]
  float m_i[2] = {-1e30f, -1e30f};          // running max per q (col = lr)
  float l_i[2] = {0.f, 0.f};                // running denom

  for (int t = 0; t < NTOK / 64; ++t) {
    __syncthreads();  // prior iter's Ks/Vs reads complete
#pragma unroll
    for (int p = 0; p < 2; ++p) {
      int r = wv * 16 + p * 8 + srow;
      *(int4*)(Ks + r * PSTR + soff) =
          *(const int4*)(kg + (size_t)(t * 64 + r) * QKVS + soff);
      *(int4*)(Vs + r * PSTR + soff) =
          *(const int4*)(vg + (size_t)r * NTOK + t * 64 + soff);
    }
    __syncthreads();

    // S^T = K @ Q^T : rows = 64 keys (4 tiles), cols = 32 q (2 tiles)
    v4f sac[4][2] = {};
#pragma unroll
    for (int s = 0; s < 2; ++s) {
      short8 kf[4];
#pragma unroll
      for (int mt = 0; mt < 4; ++mt)
        kf[mt] =
            *(const short8*)(Ks + (mt * 16 + lr) * PSTR + s * 32 + quad * 8);
#pragma unroll
      for (int mt = 0; mt < 4; ++mt)
#pragma unroll
        for (int n = 0; n < 2; ++n)
          sac[mt][n] = __builtin_amdgcn_mfma_f32_16x16x32_bf16(
              kf[mt], qf[n][s], sac[mt][n], 0, 0, 0);
    }

    // online softmax per q-group; stats indexed by q = lr, replicated
#pragma unroll
    for (int n = 0; n < 2; ++n) {
      float mx = -1e30f;
#pragma unroll
      for (int mt = 0; mt < 4; ++mt)
#pragma unroll
        for (int r = 0; r < 4; ++r) mx = fmaxf(mx, sac[mt][n][r]);
      mx = fmaxf(mx, __shfl_xor(mx, 16, 64));
      mx = fmaxf(mx, __shfl_xor(mx, 32, 64));
      float mnew = fmaxf(m_i[n], mx);
      float alpha = __builtin_amdgcn_exp2f(m_i[n] - mnew);
      m_i[n] = mnew;
      float sum = 0.f;
#pragma unroll
      for (int mt = 0; mt < 4; ++mt) {
#pragma unroll
        for (int r = 0; r < 4; ++r) {
          float p = __builtin_amdgcn_exp2f(sac[mt][n][r] - mnew);
          sac[mt][n][r] = p;
          sum += p;
        }
        // write P[q][key] (bf16) into per-wave LDS; key = mt*16+quad*4+reg
        *(uint2*)(Pw + (n * 16 + lr) * PSTR + mt * 16 + quad * 4) =
            make_uint2(pkrh(sac[mt][n][0], sac[mt][n][1]),
                       pkrh(sac[mt][n][2], sac[mt][n][3]));
      }
      sum += __shfl_xor(sum, 16, 64);
      sum += __shfl_xor(sum, 32, 64);
      l_i[n] = l_i[n] * alpha + sum;
      // rescale O: alpha lives at lane c=q; O rows are q=quad*4+reg
#pragma unroll
      for (int r = 0; r < 4; ++r) {
        float ao = __shfl(alpha, quad * 4 + r, 64);
#pragma unroll
        for (int j = 0; j < 4; ++j) oac[n][j][r] *= ao;
      }
    }

    // O += P @ V (A-frags from Pw, B-frags from Vs; in-wave dependency only)
#pragma unroll
    for (int s = 0; s < 2; ++s) {
      short8 pf[2], vf[4];
#pragma unroll
      for (int i = 0; i < 2; ++i)
        pf[i] =
            *(const short8*)(Pw + (i * 16 + lr) * PSTR + s * 32 + quad * 8);
#pragma unroll
      for (int j = 0; j < 4; ++j)
        vf[j] =
            *(const short8*)(Vs + (j * 16 + lr) * PSTR + s * 32 + quad * 8);
#pragma unroll
      for (int i = 0; i < 2; ++i)
#pragma unroll
        for (int j = 0; j < 4; ++j)
          oac[i][j] = __builtin_amdgcn_mfma_f32_16x16x32_bf16(
              pf[i], vf[j], oac[i][j], 0, 0, 0);
    }
  }

  unsigned short* ob =
      o + (size_t)(bb * NTOK + q0 + wv * 32) * INNER + hh * DHEAD;
#pragma unroll
  for (int i = 0; i < 2; ++i) {
    float inv = 1.0f / l_i[i];
#pragma unroll
    for (int r = 0; r < 4; ++r) {
      float il = __shfl(inv, quad * 4 + r, 64);
      int row = i * 16 + quad * 4 + r;
#pragma unroll
      for (int j = 0; j < 4; ++j)
        ob[(size_t)row * INNER + 16 * j + lr] = f2b(oac[i][j][r] * il);
    }
  }
}

// ---------------------------------------------------------------------------
extern "C" void kernel_launch(void* const* d_in, const int* in_sizes, int n_in,
                              void* d_out, int out_size, void* d_ws,
                              size_t ws_size, hipStream_t stream) {
  const float* x      = (const float*)d_in[0];
  const float* w_conv = (const float*)d_in[1];
  const float* b_conv = (const float*)d_in[2];
  const float* pos    = (const float*)d_in[3];
  const float* ln1w   = (const float*)d_in[4];
  const float* ln1b   = (const float*)d_in[5];
  const float* qkvw   = (const float*)d_in[6];
  const float* outw   = (const float*)d_in[7];
  const float* outb   = (const float*)d_in[8];
  const float* ln2w   = (const float*)d_in[9];
  const float* ln2b   = (const float*)d_in[10];
  const float* w1     = (const float*)d_in[11];
  const float* b1     = (const float*)d_in[12];
  const float* w2     = (const float*)d_in[13];
  const float* b2     = (const float*)d_in[14];

  char* ws = (char*)d_ws;
  float* h            = (float*)(ws + 0);                 // 25,165,824 B
  unsigned short* big = (unsigned short*)(ws + 25165824); // 50,331,648 B
  unsigned short* y   = (unsigned short*)(ws + 75497472); // 12,582,912 B
  unsigned short* wq  = (unsigned short*)(ws + 88080384); //  3,538,944 B
  unsigned short* wo  = (unsigned short*)(ws + 91619328); //  1,179,648 B
  unsigned short* w1t = (unsigned short*)(ws + 92798976); //  4,718,592 B
  unsigned short* w2t = (unsigned short*)(ws + 97517568); //  4,718,592 B
  unsigned short* wc  = (unsigned short*)(ws + 102236160);//    294,912 B
  unsigned short* vt  = (unsigned short*)(ws + 102531072);// 12,582,912 B
  float* outp = (float*)d_out;

  dim3 blk(256);

  cast_kernel<<<dim3((DMODEL * KPATCH + 255) / 256), blk, 0, stream>>>(
      w_conv, wc, DMODEL * KPATCH);
  im2col_kernel<<<dim3((MROWS * KPATCH + 255) / 256), blk, 0, stream>>>(x, big);
  // patch embed: [8192,192] @ wc[768,192]^T + b_conv + pos -> h fp32
  mfma_gemm_kernel<4, 0><<<dim3(DMODEL / 128, MROWS / 128), blk, 0, stream>>>(
      big, wc, b_conv, pos, h, MROWS, DMODEL, KPATCH);

  for (int l = 0; l < DEPTH; ++l) {
    transpose_cast_kernel<<<dim3(QKVS / 32, DMODEL / 32), blk, 0, stream>>>(
        qkvw + (size_t)l * DMODEL * QKVS, wq, DMODEL, QKVS);
    ln_kernel<<<dim3(MROWS), blk, 0, stream>>>(h, ln1w + l * DMODEL,
                                               ln1b + l * DMODEL, y);
    mfma_gemm_kernel<5, 1><<<dim3(QKVS / 128, MROWS / 128), blk, 0, stream>>>(
        y, wq, nullptr, nullptr, big, MROWS, QKVS, DMODEL);
    vtrans_kernel<<<dim3(NTOK / 32, DHEAD / 32, BATCH * HEADS), blk, 0,
                    stream>>>(big, vt);
    attn_kernel<<<dim3(NTOK / 128, HEADS, BATCH), blk, 0, stream>>>(big, vt, y);
    transpose_cast_kernel<<<dim3(DMODEL / 32, INNER / 32), blk, 0, stream>>>(
        outw + (size_t)l * INNER * DMODEL, wo, INNER, DMODEL);
    mfma_gemm_kernel<2, 0><<<dim3(DMODEL / 128, MROWS / 128), blk, 0, stream>>>(
        y, wo, outb + l * DMODEL, h, h, MROWS, DMODEL, INNER);
    ln_kernel<<<dim3(MROWS), blk, 0, stream>>>(h, ln2w + l * DMODEL,
                                               ln2b + l * DMODEL, y);
    transpose_cast_kernel<<<dim3(MLPDIM / 32, DMODEL / 32), blk, 0, stream>>>(
        w1 + (size_t)l * DMODEL * MLPDIM, w1t, DMODEL, MLPDIM);
    mfma_gemm_kernel<3, 1><<<dim3(MLPDIM / 128, MROWS / 128), blk, 0, stream>>>(
        y, w1t, b1 + l * MLPDIM, nullptr, big, MROWS, MLPDIM, DMODEL);
    transpose_cast_kernel<<<dim3(DMODEL / 32, MLPDIM / 32), blk, 0, stream>>>(
        w2 + (size_t)l * MLPDIM * DMODEL, w2t, MLPDIM, DMODEL);
    float* dst = (l == DEPTH - 1) ? outp : h;
    mfma_gemm_kernel<2, 0><<<dim3(DMODEL / 128, MROWS / 128), blk, 0, stream>>>(
        big, w2t, b2 + l * DMODEL, h, dst, MROWS, DMODEL, MLPDIM);
  }
}